// Round 6
// baseline (138.180 us; speedup 1.0000x reference)
//
#include <hip/hip_runtime.h>

#define NREL1  12   // NREL + 1 relation matrices
#define NN     128  // neighbours
#define EE     128  // in-features
#define FF     128  // out-features
#define BV     192  // B * V
#define RK     (NREL1 * EE)   // 1536
#define NTILE  12             // 16-bv tiles
#define KSPLIT 4
#define KCHUNK (RK / KSPLIT)  // 384

// ws layout (floats):
//   [0, 3072)                 wa  (Wa1[12][128] | Wa2[12][128])
//   [3072, 3088)              tile ticket counters (int)
//   [4096, 4096 + BV*RK)      S[bv][r*128+e]
#define WS_WA  0
#define WS_CNT 3072
#define WS_S   4096

// K0: wa rows (wave per (r,e) row, coalesced) + zero out + zero counters.
__global__ __launch_bounds__(256) void prep_kernel(const float* __restrict__ W,
                                                   const float* __restrict__ a,
                                                   float* __restrict__ ws,
                                                   float* __restrict__ out) {
    const int w    = blockIdx.x * 4 + (threadIdx.x >> 6);  // 1536 waves
    const int lane = threadIdx.x & 63;
    const int r = w >> 7, e = w & 127;
    const float2 wv = *(const float2*)(W + (size_t)(r * EE + e) * FF + lane * 2);
    const float2 a1 = *(const float2*)(a + lane * 2);
    const float2 a2 = *(const float2*)(a + FF + lane * 2);
    float d1 = wv.x * a1.x + wv.y * a1.y;
    float d2 = wv.x * a2.x + wv.y * a2.y;
#pragma unroll
    for (int off = 32; off; off >>= 1) {
        d1 += __shfl_xor(d1, off);
        d2 += __shfl_xor(d2, off);
    }
    if (lane == 0) {
        ws[WS_WA + r * EE + e]      = d1;
        ws[WS_WA + RK + r * EE + e] = d2;
    }
    const int gid = blockIdx.x * 256 + threadIdx.x;
    if (gid < BV * FF) out[gid] = 0.f;
    if (gid < 16) ((int*)(ws + WS_CNT))[gid] = 0;
}

// K1: block per bv. Prefetch fe/ne to regs -> logits (shfl) -> softmax ->
// 16-copy LDS scatter -> reduce + S to ws -> ticket; last-4 per tile run
// the split-K GEMM tail (out += S_tile @ W_chunk, atomicAdd).
__global__ __launch_bounds__(1024) void gat_main(const float* __restrict__ fe,
                                                 const float* __restrict__ ne,
                                                 const int* __restrict__ widx,
                                                 const float* __restrict__ ind,
                                                 const float* __restrict__ W,
                                                 float* __restrict__ ws,
                                                 float* __restrict__ out) {
    __shared__ float s16[16][RK];   // 96 KB; reused as S-tile in GEMM tail
    __shared__ float wa[2 * RK];    // 12 KB
    __shared__ float e_lds[NN];
    __shared__ float attn[NN];
    __shared__ int   idx[NN];
    __shared__ int   ticket_s;

    const int bv   = blockIdx.x;
    const int tid  = threadIdx.x;
    const int wave = tid >> 6;
    const int lane = tid & 63;
    const int l32  = lane & 31;
    const int half = lane >> 5;   // 0: ne/wa1 side, 1: fe/wa2 side

    const float* ne_bv = ne + (size_t)bv * NN * EE;
    const float* fe_bv = fe + (size_t)bv * NN * EE;

    if (tid < NN) idx[tid] = widx[bv * NN + tid];

    // prefetch this bv's rows: 8 edges/wave, lane holds one e-quad
    float4 xr[8];
    {
        const float* base = (half ? fe_bv : ne_bv) + l32 * 4;
#pragma unroll
        for (int i = 0; i < 8; ++i)
            xr[i] = *(const float4*)(base + (wave * 8 + i) * EE);
    }

    // stage wa (L2) -> LDS, zero scatter copies
    for (int q = tid; q < 2 * RK / 4; q += 1024)
        *(float4*)&wa[q * 4] = *(const float4*)(ws + WS_WA + q * 4);
    {
        const float4 z = {0.f, 0.f, 0.f, 0.f};
        for (int q = tid; q < 16 * RK / 4; q += 1024)
            ((float4*)&s16[0][0])[q] = z;
    }
    __syncthreads();

    // Phase A: logits; lanes<32 contribute ne.wa1, lanes>=32 fe.wa2
#pragma unroll
    for (int i = 0; i < 8; ++i) {
        const int n = wave * 8 + i;
        const int r = idx[n];
        const float4 wq = *(const float4*)&wa[half * RK + r * EE + l32 * 4];
        float d = xr[i].x * wq.x + xr[i].y * wq.y + xr[i].z * wq.z + xr[i].w * wq.w;
#pragma unroll
        for (int off = 32; off; off >>= 1) d += __shfl_xor(d, off);
        if (lane == 0) e_lds[n] = d > 0.f ? d : 0.2f * d;
    }
    __syncthreads();

    // Phase B: softmax over neighbours + indicator mask (wave 0)
    if (tid < 64) {
        float v0 = e_lds[tid], v1 = e_lds[tid + 64];
        float m = fmaxf(v0, v1);
#pragma unroll
        for (int off = 32; off; off >>= 1) m = fmaxf(m, __shfl_xor(m, off));
        float ex0 = expf(v0 - m), ex1 = expf(v1 - m);
        float ssum = ex0 + ex1;
#pragma unroll
        for (int off = 32; off; off >>= 1) ssum += __shfl_xor(ssum, off);
        float inv = 1.f / ssum;
        attn[tid]      = ex0 * inv * ind[bv * NN + tid];
        attn[tid + 64] = ex1 * inv * ind[bv * NN + tid + 64];
    }
    __syncthreads();

    // Phase C: scatter from regs into this wave's private copy
    if (half == 0) {
        float* sc = s16[wave];
#pragma unroll
        for (int i = 0; i < 8; ++i) {
            const int n = wave * 8 + i;
            const float an = attn[n];
            float* p = sc + idx[n] * EE + l32 * 4;
            float4 cur = *(const float4*)p;
            cur.x += an * xr[i].x; cur.y += an * xr[i].y;
            cur.z += an * xr[i].z; cur.w += an * xr[i].w;
            *(float4*)p = cur;
        }
    }
    __syncthreads();

    // reduce 16 copies -> S row in ws
    for (int q = tid; q < RK / 4; q += 1024) {
        float4 v = {0.f, 0.f, 0.f, 0.f};
#pragma unroll
        for (int c = 0; c < 16; ++c) {
            const float4 t = *(const float4*)&s16[c][q * 4];
            v.x += t.x; v.y += t.y; v.z += t.z; v.w += t.w;
        }
        *(float4*)(ws + WS_S + (size_t)bv * RK + q * 4) = v;
    }
    __threadfence();
    __syncthreads();

    // completion ticket for this 16-bv tile
    if (tid == 0)
        ticket_s = atomicAdd((int*)(ws + WS_CNT) + (bv >> 4), 1);
    __syncthreads();
    const int tk = ticket_s;
    if (tk < NTILE + KSPLIT - 16) {}   // (dead; keep structure simple)
    if (tk < 12) return;               // not an owner

    // ---- GEMM tail: out[tile rows] += S_tile[:, k0:k0+384] @ W[k0:k0+384, :]
    const int ks   = tk - 12;
    const int tile = bv >> 4;
    const int bv0  = tile * 16;
    const int k0   = ks * KCHUNK;
    __threadfence();   // acquire: make other blocks' S writes visible

    float* st = &s16[0][0];            // st[b*KCHUNK + kk], 24 KB
    for (int q = tid; q < 16 * KCHUNK / 4; q += 1024) {
        const int b = q / (KCHUNK / 4), kq = q % (KCHUNK / 4);
        *(float4*)&st[b * KCHUNK + kq * 4] =
            *(const float4*)(ws + WS_S + (size_t)(bv0 + b) * RK + k0 + kq * 4);
    }
    __syncthreads();

    if (tid < 512) {
        const int b  = tid >> 5;          // 0..15: bv row in tile
        const int f4 = (tid & 31) * 4;    // f-quad
        float4 acc = {0.f, 0.f, 0.f, 0.f};
        const float* sb = st + b * KCHUNK;
        const float* Wp = W + (size_t)k0 * FF + f4;
#pragma unroll 2
        for (int kq = 0; kq < KCHUNK / 4; ++kq) {
            const float4 sv = *(const float4*)&sb[kq * 4];
            const float4 w0 = *(const float4*)(Wp + (size_t)(kq * 4 + 0) * FF);
            const float4 w1 = *(const float4*)(Wp + (size_t)(kq * 4 + 1) * FF);
            const float4 w2 = *(const float4*)(Wp + (size_t)(kq * 4 + 2) * FF);
            const float4 w3 = *(const float4*)(Wp + (size_t)(kq * 4 + 3) * FF);
            acc.x += sv.x * w0.x + sv.y * w1.x + sv.z * w2.x + sv.w * w3.x;
            acc.y += sv.x * w0.y + sv.y * w1.y + sv.z * w2.y + sv.w * w3.y;
            acc.z += sv.x * w0.z + sv.y * w1.z + sv.z * w2.z + sv.w * w3.z;
            acc.w += sv.x * w0.w + sv.y * w1.w + sv.z * w2.w + sv.w * w3.w;
        }
        float* op = out + (size_t)(bv0 + b) * FF + f4;
        atomicAdd(op + 0, acc.x);
        atomicAdd(op + 1, acc.y);
        atomicAdd(op + 2, acc.z);
        atomicAdd(op + 3, acc.w);
    }
}

extern "C" void kernel_launch(void* const* d_in, const int* in_sizes, int n_in,
                              void* d_out, int out_size, void* d_ws, size_t ws_size,
                              hipStream_t stream) {
    const float* fe  = (const float*)d_in[0];  // feature_embed   (B,V,N,E)
    const float* ne  = (const float*)d_in[1];  // neighbour_embed (B,V,N,E)
    const int*   wi  = (const int*)d_in[2];    // w_index (B,V,N)
    const float* ind = (const float*)d_in[3];  // indicator (B,V,N)
    const float* W   = (const float*)d_in[4];  // (12,E,F)
    const float* a   = (const float*)d_in[5];  // (2F,1)
    float* out = (float*)d_out;                // (B,V,F)
    float* ws  = (float*)d_ws;

    prep_kernel<<<RK / 4, 256, 0, stream>>>(W, a, ws, out);
    gat_main<<<BV, 1024, 0, stream>>>(fe, ne, wi, ind, W, ws, out);
}

// Round 7
// 33.586 us; speedup vs baseline: 4.1142x; 4.1142x over previous
//
#include <hip/hip_runtime.h>

#define NREL1  12   // NREL + 1 relation matrices
#define NN     128  // neighbours
#define EE     128  // in-features
#define FF     128  // out-features
#define BV     192  // B * V
#define RK     (NREL1 * EE)   // 1536

// ws layout (floats):
//   [0, 3072)             wa  (Wa1[12][128] | Wa2[12][128])
//   [4096, 4096 + BV*RK)  S[bv][r*128+e]
#define WS_WA  0
#define WS_S   4096

// K0: wa rows (wave per (r,e), coalesced W read once aggregate) + zero out.
__global__ __launch_bounds__(256) void prep_kernel(const float* __restrict__ W,
                                                   const float* __restrict__ a,
                                                   float* __restrict__ ws,
                                                   float* __restrict__ out) {
    const int w    = blockIdx.x * 4 + (threadIdx.x >> 6);  // 1536 waves
    const int lane = threadIdx.x & 63;
    const int r = w >> 7, e = w & 127;
    const float2 wv = *(const float2*)(W + (size_t)(r * EE + e) * FF + lane * 2);
    const float2 a1 = *(const float2*)(a + lane * 2);
    const float2 a2 = *(const float2*)(a + FF + lane * 2);
    float d1 = wv.x * a1.x + wv.y * a1.y;
    float d2 = wv.x * a2.x + wv.y * a2.y;
#pragma unroll
    for (int off = 32; off; off >>= 1) {
        d1 += __shfl_xor(d1, off);
        d2 += __shfl_xor(d2, off);
    }
    if (lane == 0) {
        ws[WS_WA + r * EE + e]      = d1;
        ws[WS_WA + RK + r * EE + e] = d2;
    }
    const int gid = blockIdx.x * 256 + threadIdx.x;
    if (gid < BV * FF) out[gid] = 0.f;
}

// K1: block per bv, 512 threads (8 waves). No W access.
// prefetch fe/ne to regs (16 edges/wave; lanes<32 ne, >=32 fe, l32 owns quad)
// -> logits (64-lane butterfly) -> softmax+mask -> scatter from regs into
// per-wave LDS copy -> reduce 8 copies -> S row to ws.
__global__ __launch_bounds__(512) void attn_kernel(const float* __restrict__ fe,
                                                   const float* __restrict__ ne,
                                                   const int* __restrict__ widx,
                                                   const float* __restrict__ ind,
                                                   const float* __restrict__ ws_r,
                                                   float* __restrict__ ws_w) {
    __shared__ float wa[2 * RK];     // 12 KB
    __shared__ float s8[8][RK];      // 48 KB
    __shared__ float e_lds[NN];
    __shared__ float attn[NN];
    __shared__ int   idx[NN];

    const int bv   = blockIdx.x;
    const int tid  = threadIdx.x;
    const int wave = tid >> 6;
    const int lane = tid & 63;
    const int l32  = lane & 31;
    const int half = lane >> 5;   // 0: ne/wa1 side, 1: fe/wa2 side

    const float* ne_bv = ne + (size_t)bv * NN * EE;
    const float* fe_bv = fe + (size_t)bv * NN * EE;

    if (tid < NN) idx[tid] = widx[bv * NN + tid];

    // prefetch: 16 edges per wave, lane holds one e-quad of ne (or fe)
    float4 xr[16];
    {
        const float* base = (half ? fe_bv : ne_bv) + l32 * 4;
#pragma unroll
        for (int i = 0; i < 16; ++i)
            xr[i] = *(const float4*)(base + (wave * 16 + i) * EE);
    }

    // stage wa (L2) -> LDS; zero scatter copies
    for (int q = tid; q < 2 * RK / 4; q += 512)
        *(float4*)&wa[q * 4] = *(const float4*)(ws_r + WS_WA + q * 4);
    {
        const float4 z = {0.f, 0.f, 0.f, 0.f};
        for (int q = tid; q < 8 * RK / 4; q += 512)
            ((float4*)&s8[0][0])[q] = z;
    }
    __syncthreads();

    // Phase A: logits; lanes<32 contribute ne.wa1, lanes>=32 fe.wa2
#pragma unroll
    for (int i = 0; i < 16; ++i) {
        const int n = wave * 16 + i;
        const int r = idx[n];
        const float4 wq = *(const float4*)&wa[half * RK + r * EE + l32 * 4];
        float d = xr[i].x * wq.x + xr[i].y * wq.y + xr[i].z * wq.z + xr[i].w * wq.w;
#pragma unroll
        for (int off = 32; off; off >>= 1) d += __shfl_xor(d, off);
        if (lane == 0) e_lds[n] = d > 0.f ? d : 0.2f * d;
    }
    __syncthreads();

    // Phase B: softmax over neighbours + indicator mask (wave 0)
    if (tid < 64) {
        float v0 = e_lds[tid], v1 = e_lds[tid + 64];
        float m = fmaxf(v0, v1);
#pragma unroll
        for (int off = 32; off; off >>= 1) m = fmaxf(m, __shfl_xor(m, off));
        float ex0 = expf(v0 - m), ex1 = expf(v1 - m);
        float ssum = ex0 + ex1;
#pragma unroll
        for (int off = 32; off; off >>= 1) ssum += __shfl_xor(ssum, off);
        float inv = 1.f / ssum;
        attn[tid]      = ex0 * inv * ind[bv * NN + tid];
        attn[tid + 64] = ex1 * inv * ind[bv * NN + tid + 64];
    }
    __syncthreads();

    // Phase C: scatter from regs into this wave's private copy (ne side only)
    if (half == 0) {
        float* sc = s8[wave];
#pragma unroll
        for (int i = 0; i < 16; ++i) {
            const int n = wave * 16 + i;
            const float an = attn[n];
            float* p = sc + idx[n] * EE + l32 * 4;
            float4 cur = *(const float4*)p;
            cur.x += an * xr[i].x; cur.y += an * xr[i].y;
            cur.z += an * xr[i].z; cur.w += an * xr[i].w;
            *(float4*)p = cur;
        }
    }
    __syncthreads();

    // reduce 8 copies -> S row in ws (coalesced float4 writes)
    for (int q = tid; q < RK / 4; q += 512) {
        float4 v = {0.f, 0.f, 0.f, 0.f};
#pragma unroll
        for (int c = 0; c < 8; ++c) {
            const float4 t = *(const float4*)&s8[c][q * 4];
            v.x += t.x; v.y += t.y; v.z += t.z; v.w += t.w;
        }
        *(float4*)(ws_w + WS_S + (size_t)bv * RK + q * 4) = v;
    }
}

// K2: out[bv0+b][f] += sum_{k in slice} S[bv0+b][k] * W[k][f]
// grid (12 bv-tiles, 8 K-splits of 192), 256 thr.
// thread = (fq 0..31, bg 0..3, kh 0..1): 16 acc (4 b x 4 f), W from L2,
// S transposed in LDS (pad 20 -> 2-way bank, free).
__global__ __launch_bounds__(256) void gemm_kernel(const float* __restrict__ ws_r,
                                                   const float* __restrict__ W,
                                                   float* __restrict__ out) {
    __shared__ float st[192][20];   // 15 KB, S-slice transposed [k][b]

    const int bv0 = blockIdx.x * 16;
    const int k0  = blockIdx.y * 192;
    const int tid = threadIdx.x;

    // stage S slice transposed: 16 b x 192 k
    for (int q = tid; q < 768; q += 256) {
        const int b = q / 48, kk4 = q % 48;
        const float4 v = *(const float4*)(ws_r + WS_S + (size_t)(bv0 + b) * RK + k0 + kk4 * 4);
        st[kk4 * 4 + 0][b] = v.x;
        st[kk4 * 4 + 1][b] = v.y;
        st[kk4 * 4 + 2][b] = v.z;
        st[kk4 * 4 + 3][b] = v.w;
    }
    __syncthreads();

    const int fq = tid & 31;          // f-quad
    const int bg = (tid >> 5) & 3;    // b-quad
    const int kh = tid >> 7;          // k-half of slice

    float4 acc[4] = {{0,0,0,0},{0,0,0,0},{0,0,0,0},{0,0,0,0}};
    const float* Wp = W + (size_t)(k0 + kh * 96) * FF + fq * 4;

#pragma unroll 4
    for (int k = 0; k < 96; ++k) {
        const float4 w4 = *(const float4*)(Wp + (size_t)k * FF);
        const float* sp = &st[kh * 96 + k][bg * 4];
#pragma unroll
        for (int j = 0; j < 4; ++j) {
            const float sv = sp[j];
            acc[j].x += sv * w4.x; acc[j].y += sv * w4.y;
            acc[j].z += sv * w4.z; acc[j].w += sv * w4.w;
        }
    }

#pragma unroll
    for (int j = 0; j < 4; ++j) {
        float* op = out + (size_t)(bv0 + bg * 4 + j) * FF + fq * 4;
        atomicAdd(op + 0, acc[j].x);
        atomicAdd(op + 1, acc[j].y);
        atomicAdd(op + 2, acc[j].z);
        atomicAdd(op + 3, acc[j].w);
    }
}

extern "C" void kernel_launch(void* const* d_in, const int* in_sizes, int n_in,
                              void* d_out, int out_size, void* d_ws, size_t ws_size,
                              hipStream_t stream) {
    const float* fe  = (const float*)d_in[0];  // feature_embed   (B,V,N,E)
    const float* ne  = (const float*)d_in[1];  // neighbour_embed (B,V,N,E)
    const int*   wi  = (const int*)d_in[2];    // w_index (B,V,N)
    const float* ind = (const float*)d_in[3];  // indicator (B,V,N)
    const float* W   = (const float*)d_in[4];  // (12,E,F)
    const float* a   = (const float*)d_in[5];  // (2F,1)
    float* out = (float*)d_out;                // (B,V,F)
    float* ws  = (float*)d_ws;

    prep_kernel<<<RK / 4, 256, 0, stream>>>(W, a, ws, out);
    attn_kernel<<<BV, 512, 0, stream>>>(fe, ne, wi, ind, ws, ws);
    gemm_kernel<<<dim3(12, 8), 256, 0, stream>>>(ws, W, out);
}